// Round 4
// baseline (89.655 us; speedup 1.0000x reference)
//
#include <hip/hip_runtime.h>
#include <hip/hip_fp16.h>

typedef _Float16 f16x8 __attribute__((ext_vector_type(8)));
typedef _Float16 f16x4 __attribute__((ext_vector_type(4)));
typedef float    f32x4 __attribute__((ext_vector_type(4)));

#define NB   32
#define SEQ  1024
#define EDIM 768
#define HD   64
#define MTOT (NB * SEQ)
#define LOG2E 1.44269504088896340736f

// ---------------- kernel 0: pack weights -> Wt fp16 [192][768], Wt[c][e] = W[e][c] ----
__global__ __launch_bounds__(256) void pack_w(const float* __restrict__ Wq,
                                              const float* __restrict__ Wk,
                                              const float* __restrict__ Wv,
                                              _Float16* __restrict__ Wt) {
    int c = blockIdx.x;  // 0..191
    const float* src = (c < 64) ? Wq : (c < 128) ? Wk : Wv;
    int cc = c & 63;
    for (int e = threadIdx.x; e < EDIM; e += 256)
        Wt[(size_t)c * EDIM + e] = (_Float16)src[(size_t)e * HD + cc];
}

// ---------------- kernel 1: QKV projection ------------------------------------------
// 128x192 tile, 4 waves x 32 rows. A-frags direct from global (no x LDS),
// Wt double-buffered in LDS. Emits q16,k16 (row-major), v16t (transposed),
// LN partials, per-row K sums.
__global__ __launch_bounds__(256) void proj_kernel(const float* __restrict__ x,
                                                   const _Float16* __restrict__ Wt,
                                                   _Float16* __restrict__ q16,
                                                   _Float16* __restrict__ k16,
                                                   _Float16* __restrict__ v16t,
                                                   float* __restrict__ part,
                                                   float* __restrict__ ksum) {
    __shared__ _Float16 wsh[2][192][72];
    __shared__ float red[4][6];
    const int tid = threadIdx.x, wave = tid >> 6, lane = tid & 63;
    const int lr = lane & 15, lk = (lane >> 4) * 8, lrow = (lane >> 4) * 4;
    const int m0 = blockIdx.x * 128;
    const int bb = blockIdx.x >> 3;                 // batch index (128*8 = 1024)
    const float* xr0 = x + (size_t)(m0 + wave * 32 + lr) * EDIM;
    const float* xr1 = xr0 + (size_t)16 * EDIM;

    f32x4 acc[2][12] = {};
    f32x4 xv[8];
    f16x8 wv[6];

    // prologue: load x-frags(t0) + Wt tile(t0), stage wsh[0]
    xv[0] = *(const f32x4*)&xr0[lk];      xv[1] = *(const f32x4*)&xr0[lk + 4];
    xv[2] = *(const f32x4*)&xr0[32 + lk]; xv[3] = *(const f32x4*)&xr0[36 + lk];
    xv[4] = *(const f32x4*)&xr1[lk];      xv[5] = *(const f32x4*)&xr1[lk + 4];
    xv[6] = *(const f32x4*)&xr1[32 + lk]; xv[7] = *(const f32x4*)&xr1[36 + lk];
    #pragma unroll
    for (int i = 0; i < 6; ++i) {
        int lin = tid + i * 256, c = lin >> 3, c8 = (lin & 7) * 8;
        wv[i] = *(const f16x8*)&Wt[(size_t)c * EDIM + c8];
    }
    #pragma unroll
    for (int i = 0; i < 6; ++i) {
        int lin = tid + i * 256, c = lin >> 3, c8 = (lin & 7) * 8;
        *(f16x8*)&wsh[0][c][c8] = wv[i];
    }
    __syncthreads();

    for (int kt = 0; kt < 12; ++kt) {
        const int cur = kt & 1;
        f16x8 a00, a01, a10, a11;
        #pragma unroll
        for (int j = 0; j < 4; ++j) {
            a00[j] = (_Float16)xv[0][j]; a00[4 + j] = (_Float16)xv[1][j];
            a01[j] = (_Float16)xv[2][j]; a01[4 + j] = (_Float16)xv[3][j];
            a10[j] = (_Float16)xv[4][j]; a10[4 + j] = (_Float16)xv[5][j];
            a11[j] = (_Float16)xv[6][j]; a11[4 + j] = (_Float16)xv[7][j];
        }
        if (kt < 11) {       // prefetch next K-slice (regs) while MFMAs run
            const int e0 = (kt + 1) * 64;
            xv[0] = *(const f32x4*)&xr0[e0 + lk];      xv[1] = *(const f32x4*)&xr0[e0 + lk + 4];
            xv[2] = *(const f32x4*)&xr0[e0 + 32 + lk]; xv[3] = *(const f32x4*)&xr0[e0 + 36 + lk];
            xv[4] = *(const f32x4*)&xr1[e0 + lk];      xv[5] = *(const f32x4*)&xr1[e0 + lk + 4];
            xv[6] = *(const f32x4*)&xr1[e0 + 32 + lk]; xv[7] = *(const f32x4*)&xr1[e0 + 36 + lk];
            #pragma unroll
            for (int i = 0; i < 6; ++i) {
                int lin = tid + i * 256, c = lin >> 3, c8 = (lin & 7) * 8;
                wv[i] = *(const f16x8*)&Wt[(size_t)c * EDIM + e0 + c8];
            }
        }
        #pragma unroll
        for (int nb = 0; nb < 12; ++nb) {
            f16x8 b0 = *(const f16x8*)&wsh[cur][nb * 16 + lr][lk];
            f16x8 b1 = *(const f16x8*)&wsh[cur][nb * 16 + lr][32 + lk];
            acc[0][nb] = __builtin_amdgcn_mfma_f32_16x16x32_f16(a00, b0, acc[0][nb], 0, 0, 0);
            acc[0][nb] = __builtin_amdgcn_mfma_f32_16x16x32_f16(a01, b1, acc[0][nb], 0, 0, 0);
            acc[1][nb] = __builtin_amdgcn_mfma_f32_16x16x32_f16(a10, b0, acc[1][nb], 0, 0, 0);
            acc[1][nb] = __builtin_amdgcn_mfma_f32_16x16x32_f16(a11, b1, acc[1][nb], 0, 0, 0);
        }
        if (kt < 11) {
            #pragma unroll
            for (int i = 0; i < 6; ++i) {
                int lin = tid + i * 256, c = lin >> 3, c8 = (lin & 7) * 8;
                *(f16x8*)&wsh[cur ^ 1][c][c8] = wv[i];
            }
            __syncthreads();
        }
    }

    // epilogue
    const int rowin0 = (m0 & 1023) + wave * 32;      // row within batch
    #pragma unroll
    for (int rg = 0; rg < 2; ++rg) {
        const int rbase = m0 + wave * 32 + rg * 16 + lrow;
        // q16 / k16 row-major (C layout: row=lrow+j, col=lr)
        #pragma unroll
        for (int nb = 0; nb < 8; ++nb) {
            _Float16* dst = (nb < 4) ? q16 : k16;
            int lc = (nb & 3) * 16 + lr;
            #pragma unroll
            for (int j = 0; j < 4; ++j)
                dst[(size_t)(rbase + j) * HD + lc] = (_Float16)acc[rg][nb][j];
        }
        // v16t transposed: 4 consecutive rows pack into one f16x4
        #pragma unroll
        for (int nb = 8; nb < 12; ++nb) {
            int col = (nb & 3) * 16 + lr;
            f16x4 h;
            #pragma unroll
            for (int j = 0; j < 4; ++j) h[j] = (_Float16)acc[rg][nb][j];
            *(f16x4*)&v16t[((size_t)(bb * 64 + col)) * SEQ + rowin0 + rg * 16 + lrow] = h;
        }
        // per-row K sums
        #pragma unroll
        for (int j = 0; j < 4; ++j) {
            float ks = (acc[rg][4][j] + acc[rg][5][j]) + (acc[rg][6][j] + acc[rg][7][j]);
            ks += __shfl_xor(ks, 1); ks += __shfl_xor(ks, 2);
            ks += __shfl_xor(ks, 4); ks += __shfl_xor(ks, 8);
            if (lr == 0) ksum[rbase + j] = ks;
        }
    }

    // per-block LN partials (sum, sumsq) for q/k/v
    #pragma unroll
    for (int t3 = 0; t3 < 3; ++t3) {
        float s = 0.f, q = 0.f;
        #pragma unroll
        for (int rg = 0; rg < 2; ++rg)
            #pragma unroll
            for (int nb = t3 * 4; nb < t3 * 4 + 4; ++nb)
                #pragma unroll
                for (int j = 0; j < 4; ++j) { float v = acc[rg][nb][j]; s += v; q += v * v; }
        #pragma unroll
        for (int off = 1; off < 64; off <<= 1) {
            s += __shfl_xor(s, off); q += __shfl_xor(q, off);
        }
        if (lane == 0) { red[wave][t3 * 2] = s; red[wave][t3 * 2 + 1] = q; }
    }
    __syncthreads();
    if (tid < 6)
        part[blockIdx.x * 6 + tid] = red[0][tid] + red[1][tid] + red[2][tid] + red[3][tid];
}

// ---------------- kernel 2: reduce per-block partials -> per-batch mean/rstd --------
__global__ __launch_bounds__(64) void stats_reduce(const float* __restrict__ part,
                                                   float* __restrict__ stats) {
    int b = blockIdx.x, a = threadIdx.x;
    if (a < 3) {
        double s = 0.0, q = 0.0;
        for (int i = 0; i < 8; ++i) {           // 8 blocks per batch (128 rows each)
            s += (double)part[(b * 8 + i) * 6 + a * 2];
            q += (double)part[(b * 8 + i) * 6 + a * 2 + 1];
        }
        double mean = s / 65536.0;
        double var  = q / 65536.0 - mean * mean;
        stats[b * 8 + a * 2 + 0] = (float)mean;
        stats[b * 8 + a * 2 + 1] = (float)(1.0 / sqrt(var + 1e-5));
    }
}

// ---------------- kernel 3: flash attention -----------------------------------------
// K-frags direct from global (L2/L1), reg double-buffered one tile ahead.
// V staged in LDS via T14 split (load early, write after barrier). exp2 softmax.
#define ATTN_STEP(KFC, KFN, VVN, T, PRE)                                              \
  {                                                                                   \
    if (PRE) {                                                                        \
      const int kvn = ((T) + 1) * 64;                                                 \
      _Pragma("unroll")                                                               \
      for (int cb = 0; cb < 4; ++cb) {                                                \
        KFN[cb * 2]     = *(const f16x8*)&Kb[(size_t)(kvn + cb * 16 + lr) * HD + lk]; \
        KFN[cb * 2 + 1] = *(const f16x8*)&Kb[(size_t)(kvn + cb * 16 + lr) * HD + 32 + lk]; \
      }                                                                               \
      _Pragma("unroll")                                                               \
      for (int i = 0; i < 2; ++i) { int lin = tid + i * 256;                          \
        VVN[i] = *(const f16x8*)&Vtb[(size_t)(lin >> 3) * SEQ + kvn + (lin & 7) * 8]; } \
    }                                                                                 \
    f32x4 sa[4]; float adjv[4];                                                       \
    _Pragma("unroll")                                                                 \
    for (int cb = 0; cb < 4; ++cb) {                                                  \
      sa[cb] = (f32x4){0.f, 0.f, 0.f, 0.f};                                           \
      sa[cb] = __builtin_amdgcn_mfma_f32_16x16x32_f16(aq0, KFC[cb * 2],     sa[cb], 0, 0, 0); \
      sa[cb] = __builtin_amdgcn_mfma_f32_16x16x32_f16(aq1, KFC[cb * 2 + 1], sa[cb], 0, 0, 0); \
      adjv[cb] = adjscale * ksb[(T) * 64 + cb * 16 + lr];                             \
    }                                                                                 \
    _Pragma("unroll")                                                                 \
    for (int j = 0; j < 4; ++j) {                                                     \
      float sv0 = sa[0][j] * sscale - adjv[0], sv1 = sa[1][j] * sscale - adjv[1];     \
      float sv2 = sa[2][j] * sscale - adjv[2], sv3 = sa[3][j] * sscale - adjv[3];     \
      float pm = fmaxf(fmaxf(sv0, sv1), fmaxf(sv2, sv3));                             \
      pm = fmaxf(pm, __shfl_xor(pm, 1)); pm = fmaxf(pm, __shfl_xor(pm, 2));           \
      pm = fmaxf(pm, __shfl_xor(pm, 4)); pm = fmaxf(pm, __shfl_xor(pm, 8));           \
      float mnew = fmaxf(mrow[j], pm);                                                \
      float alpha = exp2f(mrow[j] - mnew); mrow[j] = mnew;                            \
      float p0 = exp2f(sv0 - mnew), p1 = exp2f(sv1 - mnew);                           \
      float p2 = exp2f(sv2 - mnew), p3 = exp2f(sv3 - mnew);                           \
      sa[0][j] = p0; sa[1][j] = p1; sa[2][j] = p2; sa[3][j] = p3;                     \
      float rs = (p0 + p1) + (p2 + p3);                                               \
      rs += __shfl_xor(rs, 1); rs += __shfl_xor(rs, 2);                               \
      rs += __shfl_xor(rs, 4); rs += __shfl_xor(rs, 8);                               \
      lsum[j] = lsum[j] * alpha + rs;                                                 \
      o[0][j] *= alpha; o[1][j] *= alpha; o[2][j] *= alpha; o[3][j] *= alpha;         \
    }                                                                                 \
    _Pragma("unroll")                                                                 \
    for (int cb = 0; cb < 4; ++cb)                                                    \
      _Pragma("unroll")                                                               \
      for (int j = 0; j < 4; ++j)                                                     \
        psm[wave][lrow + j][cb * 16 + lr] = (_Float16)sa[cb][j];                      \
    f16x8 pa0 = *(const f16x8*)&psm[wave][lr][lk];                                    \
    f16x8 pa1 = *(const f16x8*)&psm[wave][lr][32 + lk];                               \
    _Pragma("unroll")                                                                 \
    for (int db = 0; db < 4; ++db) {                                                  \
      f16x8 bv0 = *(const f16x8*)&vsm[db * 16 + lr][lk];                              \
      f16x8 bv1 = *(const f16x8*)&vsm[db * 16 + lr][32 + lk];                         \
      o[db] = __builtin_amdgcn_mfma_f32_16x16x32_f16(pa0, bv0, o[db], 0, 0, 0);       \
      o[db] = __builtin_amdgcn_mfma_f32_16x16x32_f16(pa1, bv1, o[db], 0, 0, 0);       \
    }                                                                                 \
    if (PRE) {                                                                        \
      __syncthreads();                                                                \
      _Pragma("unroll")                                                               \
      for (int i = 0; i < 2; ++i) { int lin = tid + i * 256;                          \
        *(f16x8*)&vsm[lin >> 3][(lin & 7) * 8] = VVN[i]; }                            \
      __syncthreads();                                                                \
    }                                                                                 \
  }

__global__ __launch_bounds__(256) void attn_kernel(const _Float16* __restrict__ q16,
                                                   const _Float16* __restrict__ k16,
                                                   const _Float16* __restrict__ v16t,
                                                   const float* __restrict__ stats,
                                                   const float* __restrict__ ksum,
                                                   float* __restrict__ out) {
    __shared__ _Float16 vsm[64][72];     // V^T tile [d][kv]
    __shared__ _Float16 psm[4][16][72];  // per-wave P tile
    // XCD swizzle: all 16 q-tiles of a batch share (blockIdx mod 8) -> same XCD.
    const int d_ = blockIdx.x;
    const int b = (d_ & 7) * 4 + ((d_ >> 3) & 3), qt = d_ >> 5;
    const int tid = threadIdx.x, wave = tid >> 6, lane = tid & 63;
    const int lr = lane & 15, lk = (lane >> 4) * 8, lrow = (lane >> 4) * 4;
    const float sscale = stats[b * 8 + 1] * stats[b * 8 + 3] * 0.125f * LOG2E;
    const float adjscale = sscale * stats[b * 8 + 0];
    const float mv = stats[b * 8 + 4], rv = stats[b * 8 + 5];
    const int q0 = qt * 64 + wave * 16;
    const _Float16* Qb  = q16 + ((size_t)b * SEQ + q0) * HD;
    const _Float16* Kb  = k16 + (size_t)b * SEQ * HD;
    const _Float16* Vtb = v16t + (size_t)b * HD * SEQ;
    const float* ksb = ksum + b * SEQ;

    f16x8 aq0 = *(const f16x8*)&Qb[(size_t)lr * HD + lk];
    f16x8 aq1 = *(const f16x8*)&Qb[(size_t)lr * HD + 32 + lk];

    f16x8 kfA[8], kfB[8], vvA[2], vvB[2];
    f32x4 o[4] = {};
    float mrow[4], lsum[4];
    #pragma unroll
    for (int j = 0; j < 4; ++j) { mrow[j] = -1e30f; lsum[j] = 0.f; }

    // prologue: K-frags + V tile for t=0
    #pragma unroll
    for (int cb = 0; cb < 4; ++cb) {
        kfA[cb * 2]     = *(const f16x8*)&Kb[(size_t)(cb * 16 + lr) * HD + lk];
        kfA[cb * 2 + 1] = *(const f16x8*)&Kb[(size_t)(cb * 16 + lr) * HD + 32 + lk];
    }
    #pragma unroll
    for (int i = 0; i < 2; ++i) {
        int lin = tid + i * 256;
        vvA[i] = *(const f16x8*)&Vtb[(size_t)(lin >> 3) * SEQ + (lin & 7) * 8];
    }
    #pragma unroll
    for (int i = 0; i < 2; ++i) {
        int lin = tid + i * 256;
        *(f16x8*)&vsm[lin >> 3][(lin & 7) * 8] = vvA[i];
    }
    __syncthreads();

    for (int t2 = 0; t2 < 7; ++t2) {
        ATTN_STEP(kfA, kfB, vvB, 2 * t2,     1);
        ATTN_STEP(kfB, kfA, vvA, 2 * t2 + 1, 1);
    }
    ATTN_STEP(kfA, kfB, vvB, 14, 1);
    ATTN_STEP(kfB, kfA, vvA, 15, 0);

    #pragma unroll
    for (int j = 0; j < 4; ++j) {
        float inv = 1.f / lsum[j];
        size_t row = (size_t)b * SEQ + q0 + lrow + j;
        #pragma unroll
        for (int db = 0; db < 4; ++db)
            out[row * HD + db * 16 + lr] = rv * (o[db][j] * inv - mv);
    }
}

extern "C" void kernel_launch(void* const* d_in, const int* in_sizes, int n_in,
                              void* d_out, int out_size, void* d_ws, size_t ws_size,
                              hipStream_t stream) {
    const float* x  = (const float*)d_in[0];
    const float* Wq = (const float*)d_in[1];
    const float* Wk = (const float*)d_in[2];
    const float* Wv = (const float*)d_in[3];
    float* out = (float*)d_out;
    char* ws = (char*)d_ws;

    _Float16* Wt   = (_Float16*)ws;                 // 294912 B
    float* stats   = (float*)(ws + 0x50000);        // 1 KB
    float* ksum    = (float*)(ws + 0x51000);        // 128 KB
    float* part    = (float*)(ws + 0x72000);        // 6 KB
    _Float16* q16  = (_Float16*)(ws + 0x100000);    // 4 MiB each
    _Float16* k16  = (_Float16*)(ws + 0x500000);
    _Float16* v16t = (_Float16*)(ws + 0x900000);

    pack_w<<<192, 256, 0, stream>>>(Wq, Wk, Wv, Wt);
    proj_kernel<<<MTOT / 128, 256, 0, stream>>>(x, Wt, q16, k16, v16t, part, ksum);
    stats_reduce<<<NB, 64, 0, stream>>>(part, stats);
    attn_kernel<<<NB * 16, 256, 0, stream>>>(q16, k16, v16t, stats, ksum, out);
}